// Round 9
// baseline (966.127 us; speedup 1.0000x reference)
//
#include <hip/hip_runtime.h>
#include <cfloat>
#include <cstdint>

#define B_  8
#define L_  4096
#define DM  1024
#define NH  16
#define DH  64
#define SK  45

typedef __attribute__((ext_vector_type(4))) float f32x4;
typedef _Float16 f16;
typedef __attribute__((ext_vector_type(4))) _Float16 f16x4;
typedef __attribute__((ext_vector_type(8))) _Float16 f16x8;

__device__ __forceinline__ void gload_lds16(const void* g, void* l) {
  __builtin_amdgcn_global_load_lds(
      (const __attribute__((address_space(1))) unsigned int*)g,
      (__attribute__((address_space(3))) unsigned int*)l, 16, 0, 0);
}

// XOR-swizzled f16 index into a [rows][32] f16 tile (64B rows), granule 8 f16.
__device__ __forceinline__ int swz(int row, int c) {
  return row * 32 + (c ^ (((row >> 1) & 3) << 3));
}

// ---------------- x f32 -> f16 hi ----------------
__global__ __launch_bounds__(256) void xsplit16_kernel(const float* __restrict__ x,
    f16* __restrict__ xh, int n4) {
  int i = blockIdx.x * 256 + threadIdx.x;
  int stride = gridDim.x * 256;
  for (; i < n4; i += stride) {
    f32x4 v = ((const f32x4*)x)[i];
    f16x4 h;
    #pragma unroll
    for (int j = 0; j < 4; ++j) h[j] = (f16)v[j];
    ((f16x4*)xh)[i] = h;
  }
}

// ---------------- W f32 -> f16 hi (+ scaled lo) ----------------
__global__ __launch_bounds__(256) void wsplit16_kernel(const float* __restrict__ w,
    f16* __restrict__ wh, f16* __restrict__ wl, int n4, int withlo) {
  int i = blockIdx.x * 256 + threadIdx.x;
  int stride = gridDim.x * 256;
  for (; i < n4; i += stride) {
    f32x4 v = ((const f32x4*)w)[i];
    f16x4 h, l;
    #pragma unroll
    for (int j = 0; j < 4; ++j) {
      h[j] = (f16)v[j];
      l[j] = (f16)((v[j] - (float)h[j]) * 2048.0f);
    }
    ((f16x4*)wh)[i] = h;
    if (withlo) ((f16x4*)wl)[i] = l;
  }
}

// ---------------- mean over L from XH (f16) ----------------
__global__ __launch_bounds__(256) void meansum_kernel(const f16* __restrict__ xh,
                                                      float* __restrict__ meanx) {
  int b = blockIdx.x;
  int d = blockIdx.y * 256 + threadIdx.x;
  int l0 = blockIdx.z * 256;
  const f16* p = xh + ((size_t)b * L_ + l0) * DM + d;
  float s = 0.f;
  for (int i = 0; i < 256; ++i) s += (float)p[(size_t)i * DM];
  atomicAdd(&meanx[b * DM + d], s);
}

// f32 mean fallback (small-ws diagnostic path)
__global__ __launch_bounds__(256) void meansum32_kernel(const float* __restrict__ x,
                                                        float* __restrict__ meanx) {
  int b = blockIdx.x;
  int d = blockIdx.y * 256 + threadIdx.x;
  int l0 = blockIdx.z * 256;
  const float* p = x + ((size_t)b * L_ + l0) * DM + d;
  float s = 0.f;
  for (int i = 0; i < 256; ++i) s += p[(size_t)i * DM];
  atomicAdd(&meanx[b * DM + d], s);
}

// vout(b,n) = (vin(b,:) . W[n,:]) * scale + bias[n]
__global__ __launch_bounds__(256) void proj_vec_kernel(const float* __restrict__ vin,
    const float* __restrict__ W, const float* __restrict__ bias,
    float* __restrict__ vout, float scale) {
  int g = blockIdx.x * 256 + threadIdx.x;
  int b = g >> 10, n = g & 1023;
  const float* xr = vin + b * DM;
  const float* wr = W + (size_t)n * DM;
  float a0 = 0, a1 = 0, a2 = 0, a3 = 0;
  for (int d = 0; d < DM; d += 4) {
    a0 += xr[d + 0] * wr[d + 0];
    a1 += xr[d + 1] * wr[d + 1];
    a2 += xr[d + 2] * wr[d + 2];
    a3 += xr[d + 3] * wr[d + 3];
  }
  vout[g] = ((a0 + a1) + (a2 + a3)) * scale + bias[n];
}

// ---------------- k_sample rows, f32 LDS-tiled: KS[b][s][n] ----------------
__global__ __launch_bounds__(256, 4) void ksample_kernel(const float* __restrict__ x,
    const float* __restrict__ Wk, const float* __restrict__ bk,
    const int* __restrict__ sidx, float* __restrict__ KS) {
  const int b = blockIdx.x, nc = blockIdx.y, sg = blockIdx.z;
  __shared__ float xs[5][32];
  __shared__ float wk[64][33];
  __shared__ float red[4][5][64];
  __shared__ int ls[5];
  const int tid = threadIdx.x;
  const int nl = tid & 63, kq = tid >> 6;
  if (tid < 5) ls[tid] = sidx[sg * 5 + tid];
  float acc[5] = {0.f, 0.f, 0.f, 0.f, 0.f};
  const int wrow = tid >> 2, wq = tid & 3;
  for (int kt = 0; kt < 32; ++kt) {
    const int d0 = kt * 32;
    __syncthreads();
    if (tid < 40) {
      int s = tid >> 3, q = tid & 7;
      *(f32x4*)&xs[s][q * 4] = *(const f32x4*)&x[((size_t)b * L_ + ls[s]) * DM + d0 + q * 4];
    }
    {
      const float* src = &Wk[(size_t)(nc * 64 + wrow) * DM + d0 + wq * 8];
      *(f32x4*)&wk[wrow][wq * 8]     = *(const f32x4*)src;
      *(f32x4*)&wk[wrow][wq * 8 + 4] = *(const f32x4*)(src + 4);
    }
    __syncthreads();
    #pragma unroll
    for (int i = 0; i < 2; ++i) {
      f32x4 w = *(const f32x4*)&wk[nl][kq * 8 + i * 4];
      #pragma unroll
      for (int s = 0; s < 5; ++s) {
        f32x4 xv = *(const f32x4*)&xs[s][kq * 8 + i * 4];
        acc[s] += xv[0] * w[0] + xv[1] * w[1] + xv[2] * w[2] + xv[3] * w[3];
      }
    }
  }
  #pragma unroll
  for (int s = 0; s < 5; ++s) red[kq][s][nl] = acc[s];
  __syncthreads();
  for (int t = tid; t < 5 * 64; t += 256) {
    int s = t >> 6, j = t & 63;
    int nj = nc * 64 + j;
    KS[((size_t)b * SK + sg * 5 + s) * DM + nj] =
        red[0][s][j] + red[1][s][j] + red[2][s][j] + red[3][s][j] + bk[nj];
  }
}

// ---- Q projection + FUSED msample: no Q write; emits Mb[bh][l] directly ----------
// Wave layout: wave w owns rows 64*(w>>1)..+63, head hh=w&1 (cols hh*64..+63 of the
// 128-col tile = global head 2*nt+hh). Epilogue: 2 passes through aliased LDS.
__global__ __launch_bounds__(256, 2) void gemm_qm(const float* __restrict__ x,
    const f16* __restrict__ WQH, const f16* __restrict__ WQL,
    const float* __restrict__ bq, const float* __restrict__ KS,
    float* __restrict__ Mout) {
  __shared__ __align__(16) char pool[34816 + 23040];
  f16* xh = (f16*)pool;                  // 8192
  f16* xl = (f16*)(pool + 8192);
  f16* wh = (f16*)(pool + 16384);
  f16* wl = (f16*)(pool + 24576);        // staging ends 32768
  float* Qs  = (float*)pool;             // [2][64][68] f32 = 34816 (aliased, post-loop)
  float* ksb = (float*)(pool + 34816);   // [90][64] f32 = 23040 (live whole kernel)
  const int tid = threadIdx.x;
  const int g = blockIdx.y * 8 + blockIdx.x;    // XCD = g & 7
  const int q = g >> 3;
  const int nt = q & 7;
  const int mt = (g & 7) + (q >> 3) * 8;
  const int n0 = nt * 128;
  const int m0 = mt * 128;
  const int bblk = m0 >> 12;
  const int lane = tid & 63;
  const int wave = tid >> 6;
  const int wr = (wave >> 1) * 64;
  const int wc = (wave & 1) * 64;
  const int frow = lane & 15;
  const int fk = (lane >> 4) * 8;

  // stage k_sample slices for this block's two heads (read once; L2-hot)
  for (int i = tid; i < 90 * 64; i += 256) {
    int s2 = i >> 6, d = i & 63;
    int hh = (s2 >= SK) ? 1 : 0;
    int s = s2 - hh * SK;
    ksb[i] = KS[((size_t)bblk * SK + s) * DM + (nt * 2 + hh) * 64 + d];
  }

  f32x4 aH[4][4], aL[4][4];
  #pragma unroll
  for (int i = 0; i < 4; ++i)
    #pragma unroll
    for (int j = 0; j < 4; ++j)
      #pragma unroll
      for (int z = 0; z < 4; ++z) { aH[i][j][z] = 0.f; aL[i][j][z] = 0.f; }

  const int ar = tid >> 1;
  const int ac = (tid & 1) * 16;
  const int r2 = tid >> 2;
  const int cb = (tid & 3) * 8;
  const int cbs = cb ^ (((r2 >> 1) & 3) << 3);

  for (int kt = 0; kt < 32; ++kt) {
    __syncthreads();   // kt=0: ksb staged; kt>0: prior frag reads done
    const float* gx = x + (size_t)(m0 + ar) * DM + kt * 32 + ac;
    #pragma unroll
    for (int gi = 0; gi < 4; ++gi) {
      f32x4 v = ((const f32x4*)gx)[gi];
      f16x4 h, l;
      #pragma unroll
      for (int z = 0; z < 4; ++z) {
        h[z] = (f16)v[z];
        l[z] = (f16)((v[z] - (float)h[z]) * 2048.0f);
      }
      *(f16x4*)(xh + swz(ar, ac + gi * 4)) = h;
      *(f16x4*)(xl + swz(ar, ac + gi * 4)) = l;
    }
    gload_lds16(WQH + (size_t)(n0 + r2) * DM + kt * 32 + cbs,      wh + r2 * 32 + cb);
    gload_lds16(WQH + (size_t)(n0 + r2 + 64) * DM + kt * 32 + cbs, wh + (r2 + 64) * 32 + cb);
    gload_lds16(WQL + (size_t)(n0 + r2) * DM + kt * 32 + cbs,      wl + r2 * 32 + cb);
    gload_lds16(WQL + (size_t)(n0 + r2 + 64) * DM + kt * 32 + cbs, wl + (r2 + 64) * 32 + cb);
    __syncthreads();
    f16x8 ah[4], al[4], bh[4], bl[4];
    #pragma unroll
    for (int mi = 0; mi < 4; ++mi) {
      ah[mi] = *(const f16x8*)(xh + swz(wr + mi * 16 + frow, fk));
      al[mi] = *(const f16x8*)(xl + swz(wr + mi * 16 + frow, fk));
    }
    #pragma unroll
    for (int ni = 0; ni < 4; ++ni) {
      bh[ni] = *(const f16x8*)(wh + swz(wc + ni * 16 + frow, fk));
      bl[ni] = *(const f16x8*)(wl + swz(wc + ni * 16 + frow, fk));
    }
    #pragma unroll
    for (int mi = 0; mi < 4; ++mi)
      #pragma unroll
      for (int ni = 0; ni < 4; ++ni) {
        aH[mi][ni] = __builtin_amdgcn_mfma_f32_16x16x32_f16(ah[mi], bh[ni], aH[mi][ni], 0, 0, 0);
        aL[mi][ni] = __builtin_amdgcn_mfma_f32_16x16x32_f16(ah[mi], bl[ni], aL[mi][ni], 0, 0, 0);
        aL[mi][ni] = __builtin_amdgcn_mfma_f32_16x16x32_f16(al[mi], bh[ni], aL[mi][ni], 0, 0, 0);
      }
  }
  __syncthreads();   // staging LDS dead; Qs alias safe

  // fused msample epilogue: 2 passes x (write q 2x64x64 to LDS, 2 threads/(l,h) dots)
  const int pairid = tid >> 1, half = tid & 1;
  const int lq = pairid & 63, hq = pairid >> 6;
  #pragma unroll
  for (int pass = 0; pass < 2; ++pass) {
    if ((wave >> 1) == pass) {
      #pragma unroll
      for (int mi = 0; mi < 4; ++mi)
        #pragma unroll
        for (int ni = 0; ni < 4; ++ni) {
          int col = ni * 16 + (lane & 15);
          float bc = bq[n0 + wc + col];
          #pragma unroll
          for (int j = 0; j < 4; ++j) {
            int row = mi * 16 + (lane >> 4) * 4 + j;
            Qs[((wave & 1) * 64 + row) * 68 + col] =
                aH[mi][ni][j] + aL[mi][ni][j] * (1.0f / 2048.0f) + bc;
          }
        }
    }
    __syncthreads();
    {
      float mx = -FLT_MAX, sum = 0.f;
      const float* qrow = Qs + (hq * 64 + lq) * 68 + half * 32;
      const float* krow = ksb + hq * SK * 64 + half * 32;
      for (int s = 0; s < SK; ++s) {
        float a0 = 0, a1 = 0, a2 = 0, a3 = 0;
        #pragma unroll
        for (int i = 0; i < 8; ++i) {
          f32x4 qv = *(const f32x4*)(qrow + i * 4);
          f32x4 kv = *(const f32x4*)(krow + s * 64 + i * 4);
          a0 += qv[0] * kv[0]; a1 += qv[1] * kv[1];
          a2 += qv[2] * kv[2]; a3 += qv[3] * kv[3];
        }
        float dh = (a0 + a1) + (a2 + a3);
        float dot = (dh + __shfl_xor(dh, 1)) * 0.125f;
        mx = fmaxf(mx, dot);
        sum += dot;
      }
      if (half == 0) {
        int l = (m0 & 4095) + pass * 64 + lq;
        Mout[((size_t)(bblk * NH + nt * 2 + hq)) * L_ + l] = mx - sum * (1.0f / SK);
      }
    }
    __syncthreads();
  }
}

// ---------------- top-45 per (b,h): iterative argmax ----------------
__global__ __launch_bounds__(256) void topk_kernel(const float* __restrict__ M,
                                                   int* __restrict__ topi) {
  __shared__ float vals[L_];
  __shared__ float wv[4];
  __shared__ int wi[4];
  const int bh = blockIdx.x, tid = threadIdx.x;
  for (int i = tid; i < L_; i += 256) vals[i] = M[(size_t)bh * L_ + i];
  __syncthreads();
  const int lane = tid & 63, wave = tid >> 6;
  for (int it = 0; it < SK; ++it) {
    float best = -FLT_MAX;
    int bi = 1 << 30;
    for (int i = tid; i < L_; i += 256) {
      float v = vals[i];
      if (v > best || (v == best && i < bi)) { best = v; bi = i; }
    }
    #pragma unroll
    for (int off = 32; off; off >>= 1) {
      float ov = __shfl_down(best, off);
      int oi = __shfl_down(bi, off);
      if (ov > best || (ov == best && oi < bi)) { best = ov; bi = oi; }
    }
    if (lane == 0) { wv[wave] = best; wi[wave] = bi; }
    __syncthreads();
    if (tid == 0) {
      float bb = wv[0]; int bj = wi[0];
      for (int w = 1; w < 4; ++w)
        if (wv[w] > bb || (wv[w] == bb && wi[w] < bj)) { bb = wv[w]; bj = wi[w]; }
      topi[bh * SK + it] = bj;
      vals[bj] = -FLT_MAX;
    }
    __syncthreads();
  }
}

// ---------------- q_top recompute (f16-split, exact rows): QT[bh][48][64] ---------
__global__ __launch_bounds__(256) void qtop_kernel(const float* __restrict__ x,
    const f16* __restrict__ WQH, const f16* __restrict__ WQL,
    const float* __restrict__ bq, const int* __restrict__ topi,
    f16* __restrict__ QT) {
  __shared__ f16 xsh[48 * 32], xsl[48 * 32];
  __shared__ f16 wqh[64 * 32], wql[64 * 32];
  __shared__ int lidx[48];
  const int bh = blockIdx.x;
  const int b = bh >> 4, h = bh & 15;
  const int tid = threadIdx.x;
  const int lane = tid & 63;
  const int frow = lane & 15, fk = (lane >> 4) * 8;
  if (tid < 48) lidx[tid] = (tid < SK) ? topi[bh * SK + tid] : 0;
  f32x4 accH[3][4], accL[3][4];
  #pragma unroll
  for (int i = 0; i < 3; ++i)
    #pragma unroll
    for (int j = 0; j < 4; ++j)
      #pragma unroll
      for (int z = 0; z < 4; ++z) { accH[i][j][z] = 0.f; accL[i][j][z] = 0.f; }
  const int r2 = tid >> 2, cb = (tid & 3) * 8;
  const int cbs = cb ^ (((r2 >> 1) & 3) << 3);
  for (int kt = 0; kt < 32; ++kt) {
    __syncthreads();   // kt=0: lidx ready; kt>0: prior frag reads done
    for (int i = tid; i < 48 * 32; i += 256) {
      int u = i >> 5, c = i & 31;
      float v = (u < SK) ? x[((size_t)b * L_ + lidx[u]) * DM + kt * 32 + c] : 0.f;
      f16 hv = (f16)v;
      xsh[swz(u, c)] = hv;
      xsl[swz(u, c)] = (f16)((v - (float)hv) * 2048.0f);
    }
    gload_lds16(WQH + (size_t)(h * 64 + r2) * DM + kt * 32 + cbs, wqh + r2 * 32 + cb);
    gload_lds16(WQL + (size_t)(h * 64 + r2) * DM + kt * 32 + cbs, wql + r2 * 32 + cb);
    __syncthreads();
    f16x8 ah[3], al[3], wbh[4], wbl[4];
    #pragma unroll
    for (int mu = 0; mu < 3; ++mu) {
      ah[mu] = *(const f16x8*)(xsh + swz(mu * 16 + frow, fk));
      al[mu] = *(const f16x8*)(xsl + swz(mu * 16 + frow, fk));
    }
    #pragma unroll
    for (int ni = 0; ni < 4; ++ni) {
      wbh[ni] = *(const f16x8*)(wqh + swz(ni * 16 + frow, fk));
      wbl[ni] = *(const f16x8*)(wql + swz(ni * 16 + frow, fk));
    }
    #pragma unroll
    for (int mu = 0; mu < 3; ++mu)
      #pragma unroll
      for (int ni = 0; ni < 4; ++ni) {
        accH[mu][ni] = __builtin_amdgcn_mfma_f32_16x16x32_f16(ah[mu], wbh[ni], accH[mu][ni], 0, 0, 0);
        accL[mu][ni] = __builtin_amdgcn_mfma_f32_16x16x32_f16(ah[mu], wbl[ni], accL[mu][ni], 0, 0, 0);
        accL[mu][ni] = __builtin_amdgcn_mfma_f32_16x16x32_f16(al[mu], wbh[ni], accL[mu][ni], 0, 0, 0);
      }
  }
  #pragma unroll
  for (int mu = 0; mu < 3; ++mu)
    #pragma unroll
    for (int ni = 0; ni < 4; ++ni) {
      int d = ni * 16 + (lane & 15);
      float bc = bq[h * 64 + d];
      #pragma unroll
      for (int z = 0; z < 4; ++z) {
        int u = mu * 16 + (lane >> 4) * 4 + z;
        QT[bh * 3072 + u * 64 + d] = (u < SK)
            ? (f16)(accH[mu][ni][z] + accL[mu][ni][z] * (1.0f / 2048.0f) + bc)
            : (f16)0.f;
      }
    }
}

// ---------------- fused K+V GEMM + raw scores: S f16, V f16 (d-major) to d_out ----
__global__ __launch_bounds__(256, 2) void kscore_kernel(const f16* __restrict__ XH,
    const f16* __restrict__ WKH, const f16* __restrict__ WVH,
    const float* __restrict__ bk, const float* __restrict__ bvec,
    const f16* __restrict__ QT, f16* __restrict__ S, f16* __restrict__ Vg) {
  __shared__ __align__(16) char smem[68352];
  f16* qs = (f16*)smem;
  f16* xh = (f16*)(smem + 6912);
  f16* wh = (f16*)(smem + 23296);
  f16* Kt = (f16*)(smem + 31488);
  f16* Vt = Kt;
  const int g = blockIdx.y * 128 + blockIdx.x;  // XCD = g & 7
  const int b = g & 7;
  const int p = g >> 3;
  const int jc = p >> 4;
  const int h = p & 15;
  const int bh = b * 16 + h;
  const int tid = threadIdx.x;
  const int lane = tid & 63, wave = tid >> 6;
  const int frow = lane & 15;
  const int fk = (lane >> 4) * 8;

  for (int i = tid; i < 48 * 64; i += 256)
    qs[(i >> 6) * 72 + (i & 63)] = QT[bh * 3072 + i];

  f32x4 accK[4][4], accV[4][4];
  #pragma unroll
  for (int i = 0; i < 4; ++i)
    #pragma unroll
    for (int j = 0; j < 4; ++j)
      #pragma unroll
      for (int z = 0; z < 4; ++z) { accK[i][j][z] = 0.f; accV[i][j][z] = 0.f; }

  const int r2 = tid >> 2, cb = (tid & 3) * 8;
  const int cbs = cb ^ (((r2 >> 1) & 3) << 3);
  for (int kt = 0; kt < 32; ++kt) {
    #pragma unroll
    for (int i = 0; i < 4; ++i)
      gload_lds16(XH + (size_t)(b * L_ + jc * 256 + i * 64 + r2) * DM + kt * 32 + cbs,
                  xh + (i * 64 + r2) * 32 + cb);
    gload_lds16(WKH + (size_t)(h * 64 + r2) * DM + kt * 32 + cbs, wh + r2 * 32 + cb);
    gload_lds16(WVH + (size_t)(h * 64 + r2) * DM + kt * 32 + cbs, wh + (r2 + 64) * 32 + cb);
    __syncthreads();
    f16x8 am[4], bnK[4], bnV[4];
    #pragma unroll
    for (int mi = 0; mi < 4; ++mi)
      am[mi] = *(const f16x8*)(xh + swz(wave * 64 + mi * 16 + frow, fk));
    #pragma unroll
    for (int ni = 0; ni < 4; ++ni) {
      bnK[ni] = *(const f16x8*)(wh + swz(ni * 16 + frow, fk));
      bnV[ni] = *(const f16x8*)(wh + swz(64 + ni * 16 + frow, fk));
    }
    #pragma unroll
    for (int mi = 0; mi < 4; ++mi)
      #pragma unroll
      for (int ni = 0; ni < 4; ++ni) {
        accK[mi][ni] = __builtin_amdgcn_mfma_f32_16x16x32_f16(am[mi], bnK[ni], accK[mi][ni], 0, 0, 0);
        accV[mi][ni] = __builtin_amdgcn_mfma_f32_16x16x32_f16(am[mi], bnV[ni], accV[mi][ni], 0, 0, 0);
      }
    __syncthreads();
  }

  #pragma unroll
  for (int mi = 0; mi < 4; ++mi) {
    int jl = wave * 64 + mi * 16 + (lane >> 4) * 4;
    #pragma unroll
    for (int ni = 0; ni < 4; ++ni) {
      int d = ni * 16 + (lane & 15);
      float bc = bk[h * 64 + d];
      #pragma unroll
      for (int z = 0; z < 4; ++z)
        Kt[(jl + z) * 72 + d] = (f16)(accK[mi][ni][z] + bc);
    }
  }
  __syncthreads();

  f32x4 accS[3][4];
  #pragma unroll
  for (int i = 0; i < 3; ++i)
    #pragma unroll
    for (int j = 0; j < 4; ++j)
      #pragma unroll
      for (int z = 0; z < 4; ++z) accS[i][j][z] = 0.f;
  #pragma unroll
  for (int ks = 0; ks < 2; ++ks) {
    f16x8 aq[3], bv[4];
    #pragma unroll
    for (int mu = 0; mu < 3; ++mu)
      aq[mu] = *(const f16x8*)(qs + (mu * 16 + frow) * 72 + ks * 32 + fk);
    #pragma unroll
    for (int nj = 0; nj < 4; ++nj)
      bv[nj] = *(const f16x8*)(Kt + (wave * 64 + nj * 16 + frow) * 72 + ks * 32 + fk);
    #pragma unroll
    for (int mu = 0; mu < 3; ++mu)
      #pragma unroll
      for (int nj = 0; nj < 4; ++nj)
        accS[mu][nj] = __builtin_amdgcn_mfma_f32_16x16x32_f16(aq[mu], bv[nj], accS[mu][nj], 0, 0, 0);
  }
  __syncthreads();

  #pragma unroll
  for (int mi = 0; mi < 4; ++mi) {
    int jl = wave * 64 + mi * 16 + (lane >> 4) * 4;
    #pragma unroll
    for (int ni = 0; ni < 4; ++ni) {
      int d = ni * 16 + (lane & 15);
      float bc = bvec[h * 64 + d];
      #pragma unroll
      for (int z = 0; z < 4; ++z)
        Vt[d * 264 + jl + z] = (f16)(accV[mi][ni][z] + bc);
    }
  }
  __syncthreads();

  for (int t = tid; t < 64 * 32; t += 256) {
    int d = t >> 5, j8 = t & 31;
    f16x8 v = *(const f16x8*)(Vt + d * 264 + j8 * 8);
    *(f16x8*)(Vg + ((size_t)bh * 64 + d) * L_ + jc * 256 + j8 * 8) = v;
  }

  #pragma unroll
  for (int mu = 0; mu < 3; ++mu) {
    #pragma unroll
    for (int nj = 0; nj < 4; ++nj) {
      int j = jc * 256 + wave * 64 + nj * 16 + (lane & 15);
      #pragma unroll
      for (int z = 0; z < 4; ++z) {
        int u = mu * 16 + (lane >> 4) * 4 + z;
        if (u < SK)
          S[((size_t)bh * SK + u) * L_ + j] = (f16)(accS[mu][nj][z] * 0.125f);
      }
    }
  }
}

// ---------------- PV: unnormalized exp, Z via atomics, V from global --------------
__global__ __launch_bounds__(256, 2) void pv_kernel(const f16* __restrict__ S,
    const f16* __restrict__ Vg, float* __restrict__ OT, float* __restrict__ Zb) {
  __shared__ float red[4 * 48 * 64];
  const int g = blockIdx.y * 128 + blockIdx.x;
  const int b = g & 7;
  const int p = g >> 3;
  const int jc = p >> 4;
  const int h = p & 15;
  const int bh = b * 16 + h;
  const int tid = threadIdx.x;
  const int lane = tid & 63, wave = tid >> 6;
  const int frow = lane & 15;
  const int fk = (lane >> 4) * 8;

  f32x4 accO[3][4];
  float zacc[3] = {0.f, 0.f, 0.f};
  #pragma unroll
  for (int i = 0; i < 3; ++i)
    #pragma unroll
    for (int j = 0; j < 4; ++j)
      #pragma unroll
      for (int z = 0; z < 4; ++z) accO[i][j][z] = 0.f;

  #pragma unroll
  for (int ks = 0; ks < 2; ++ks) {
    f16x8 ap[3], bv[4];
    #pragma unroll
    for (int mu = 0; mu < 3; ++mu) {
      int urow = mu * 16 + frow;
      int ur = (urow < SK) ? urow : 0;
      const f16* aptr = S + ((size_t)bh * SK + ur) * L_ + jc * 256 + wave * 64 + ks * 32 + fk;
      f16x8 raw = *(const f16x8*)aptr;
      f16x8 pp;
      float zs = 0.f;
      #pragma unroll
      for (int j = 0; j < 8; ++j) {
        f16 e = (f16)__expf((float)raw[j]);
        pp[j] = e;
        zs += (float)e;
      }
      zacc[mu] += zs;
      ap[mu] = pp;
    }
    #pragma unroll
    for (int nd = 0; nd < 4; ++nd)
      bv[nd] = *(const f16x8*)(Vg + ((size_t)bh * 64 + nd * 16 + frow) * L_ +
                               jc * 256 + wave * 64 + ks * 32 + fk);
    #pragma unroll
    for (int mu = 0; mu < 3; ++mu)
      #pragma unroll
      for (int nd = 0; nd < 4; ++nd)
        accO[mu][nd] = __builtin_amdgcn_mfma_f32_16x16x32_f16(ap[mu], bv[nd], accO[mu][nd], 0, 0, 0);
  }

  // Z partials: reduce across the 4 lane-groups sharing a row, one atomic per row
  #pragma unroll
  for (int mu = 0; mu < 3; ++mu) {
    float z = zacc[mu];
    z += __shfl_xor(z, 16);
    z += __shfl_xor(z, 32);
    int u = mu * 16 + frow;
    if ((lane >> 4) == 0 && u < SK) atomicAdd(&Zb[bh * 48 + u], z);
  }

  #pragma unroll
  for (int mu = 0; mu < 3; ++mu) {
    #pragma unroll
    for (int nd = 0; nd < 4; ++nd) {
      int d = nd * 16 + (lane & 15);
      #pragma unroll
      for (int z = 0; z < 4; ++z) {
        int u = mu * 16 + (lane >> 4) * 4 + z;
        red[wave * 3072 + u * 64 + d] = accO[mu][nd][z];
      }
    }
  }
  __syncthreads();
  for (int i = tid; i < 3072; i += 256) {
    int u = i >> 6;
    if (u < SK)
      atomicAdd(&OT[((size_t)bh * SK + u) * DH + (i & 63)],
                red[i] + red[3072 + i] + red[6144 + i] + red[9216 + i]);
  }
}

// ---------------- out = broadcast(base) ----------------
__global__ __launch_bounds__(256) void basewrite_kernel(const float* __restrict__ base,
                                                        float* __restrict__ out) {
  size_t i = (size_t)blockIdx.x * 256 + threadIdx.x;
  const size_t stride = (size_t)gridDim.x * 256;
  const size_t total = (size_t)B_ * L_ * (DM / 4);
  for (; i < total; i += stride) {
    size_t b = i >> 20;
    size_t c = i & 255;
    ((f32x4*)out)[i] = ((const f32x4*)base)[b * 256 + c];
  }
}

// ---------------- corrections: out[b, top_u, n] += (OT/Z - MV) . Wo[n, h*64:] -----
__global__ __launch_bounds__(256, 2) void corr_kernel(const float* __restrict__ OT,
    const float* __restrict__ Zb, const float* __restrict__ MV,
    const float* __restrict__ Wo, const int* __restrict__ topi,
    float* __restrict__ out) {
  __shared__ float dv[SK][64];
  __shared__ float wo[64][65];
  __shared__ float invz[SK];
  __shared__ int lidx[SK];
  const int bh = blockIdx.x, q = blockIdx.y, tid = threadIdx.x;
  const int b = bh >> 4, h = bh & 15;
  if (tid < SK) {
    invz[tid] = 1.0f / Zb[bh * 48 + tid];
    lidx[tid] = topi[bh * SK + tid];
  }
  __syncthreads();
  for (int i = tid; i < SK * 64; i += 256) {
    int u = i >> 6, d = i & 63;
    dv[u][d] = OT[((size_t)bh * SK + u) * DH + d] * invz[u] - MV[b * DM + h * DH + d];
  }
  const int nn = tid & 63, ug = tid >> 6;
  for (int c = 0; c < 4; ++c) {
    const int n0 = q * 256 + c * 64;
    __syncthreads();
    for (int t = tid; t < 1024; t += 256) {
      int row = t >> 4, vc = t & 15;
      f32x4 v = *(const f32x4*)&Wo[(size_t)(n0 + row) * DM + h * DH + vc * 4];
      *(f32x4*)&wo[row][vc * 4] = v;
    }
    __syncthreads();
    #pragma unroll
    for (int i = 0; i < 12; ++i) {
      int u = ug + i * 4;
      if (u >= SK) break;
      float a0 = 0, a1 = 0, a2 = 0, a3 = 0;
      #pragma unroll
      for (int d4 = 0; d4 < 16; ++d4) {
        f32x4 w = *(const f32x4*)&wo[nn][d4 * 4];
        f32x4 dd = *(const f32x4*)&dv[u][d4 * 4];
        a0 += dd[0] * w[0]; a1 += dd[1] * w[1];
        a2 += dd[2] * w[2]; a3 += dd[3] * w[3];
      }
      atomicAdd(&out[((size_t)b * L_ + lidx[u]) * DM + n0 + nn], (a0 + a1) + (a2 + a3));
    }
  }
}

// ---------------- workspace layout ----------------
static const size_t OFF_XH   = 0;                        // 67108864
static const size_t OFF_WQH  = OFF_XH + 67108864;        // 2097152
static const size_t OFF_WQL  = OFF_WQH + 2097152;
static const size_t OFF_WKH  = OFF_WQL + 2097152;
static const size_t OFF_WVH  = OFF_WKH + 2097152;
static const size_t OFF_KS   = OFF_WVH + 2097152;        // 1474560
static const size_t OFF_M    = OFF_KS + 1474560;         // 2097152
static const size_t OFF_TOPI = OFF_M + 2097152;          // 23040
static const size_t OFF_MEANX= OFF_TOPI + 23040;         // 32768
static const size_t OFF_MV   = OFF_MEANX + 32768;
static const size_t OFF_BASE = OFF_MV + 32768;
static const size_t OFF_ZB   = OFF_BASE + 32768;         // 128*48*4 = 24576
static const size_t OFF_QT   = OFF_ZB + 24576;           // 786432
static const size_t OFF_S    = OFF_QT + 786432;          // 47185920
static const size_t OFF_OT   = OFF_S + 47185920;         // 1474560
static const size_t WS_NEED  = OFF_OT + 1474560;

extern "C" void kernel_launch(void* const* d_in, const int* in_sizes, int n_in,
                              void* d_out, int out_size, void* d_ws, size_t ws_size,
                              hipStream_t stream) {
  const float* x  = (const float*)d_in[0];
  const float* Wq = (const float*)d_in[1];
  const float* bq = (const float*)d_in[2];
  const float* Wk = (const float*)d_in[3];
  const float* bk = (const float*)d_in[4];
  const float* Wv = (const float*)d_in[5];
  const float* bv = (const float*)d_in[6];
  const float* Wo = (const float*)d_in[7];
  const float* bo = (const float*)d_in[8];
  const int* sidx = (const int*)d_in[9];
  float* out = (float*)d_out;
  char* ws = (char*)d_ws;

  if (ws_size < WS_NEED) {
    if (ws_size < 131072) return;
    float* MEANX = (float*)(ws + 0);
    float* MV    = (float*)(ws + 32768);
    float* BASE  = (float*)(ws + 65536);
    hipMemsetAsync(MEANX, 0, 32768, stream);
    meansum32_kernel<<<dim3(B_, 4, 16), 256, 0, stream>>>(x, MEANX);
    proj_vec_kernel<<<32, 256, 0, stream>>>(MEANX, Wv, bv, MV, 1.0f / L_);
    proj_vec_kernel<<<32, 256, 0, stream>>>(MV, Wo, bo, BASE, 1.0f);
    basewrite_kernel<<<2048, 256, 0, stream>>>(BASE, out);
    return;
  }

  f16*   XH   = (f16*)(ws + OFF_XH);
  f16*   WQH  = (f16*)(ws + OFF_WQH);
  f16*   WQL  = (f16*)(ws + OFF_WQL);
  f16*   WKH  = (f16*)(ws + OFF_WKH);
  f16*   WVH  = (f16*)(ws + OFF_WVH);
  float* KS   = (float*)(ws + OFF_KS);
  float* Mb   = (float*)(ws + OFF_M);
  int*   TOPI = (int*)(ws + OFF_TOPI);
  float* MEANX= (float*)(ws + OFF_MEANX);
  float* MV   = (float*)(ws + OFF_MV);
  float* BASE = (float*)(ws + OFF_BASE);
  float* ZB   = (float*)(ws + OFF_ZB);
  f16*   QT   = (f16*)(ws + OFF_QT);
  f16*   Sb   = (f16*)(ws + OFF_S);
  float* OT   = (float*)(ws + OFF_OT);
  f16*   Vg   = (f16*)out;   // V (67 MB) lives in d_out until basewrite

  // 1. conversions / splits / zeroing
  xsplit16_kernel<<<2048, 256, 0, stream>>>(x, XH, (int)((size_t)B_ * L_ * DM / 4));
  wsplit16_kernel<<<256, 256, 0, stream>>>(Wq, WQH, WQL, DM * DM / 4, 1);
  wsplit16_kernel<<<256, 256, 0, stream>>>(Wk, WKH, WKH, DM * DM / 4, 0);
  wsplit16_kernel<<<256, 256, 0, stream>>>(Wv, WVH, WVH, DM * DM / 4, 0);
  hipMemsetAsync(MEANX, 0, 32768, stream);
  hipMemsetAsync(OT, 0, 1474560, stream);
  hipMemsetAsync(ZB, 0, 24576, stream);

  // 2. mean path (reads XH f16)
  meansum_kernel<<<dim3(B_, 4, 16), 256, 0, stream>>>(XH, MEANX);
  proj_vec_kernel<<<32, 256, 0, stream>>>(MEANX, Wv, bv, MV, 1.0f / L_);
  proj_vec_kernel<<<32, 256, 0, stream>>>(MV, Wo, bo, BASE, 1.0f);

  // 3. sampled K rows, then Q-GEMM with fused msample (no Q materialization)
  ksample_kernel<<<dim3(B_, 16, 9), 256, 0, stream>>>(x, Wk, bk, sidx, KS);
  gemm_qm<<<dim3(8, 256), 256, 0, stream>>>(x, WQH, WQL, bq, KS, Mb);

  // 4. top-k + exact q_top recompute
  topk_kernel<<<B_ * NH, 256, 0, stream>>>(Mb, TOPI);
  qtop_kernel<<<B_ * NH, 256, 0, stream>>>(x, WQH, WQL, bq, TOPI, QT);

  // 5. fused K+V GEMM + raw scores (V -> d_out), PV with inline exp + Z
  kscore_kernel<<<dim3(128, 16), 256, 0, stream>>>(XH, WKH, WVH, bk, bv, QT, Sb, Vg);
  pv_kernel<<<dim3(128, 16), 256, 0, stream>>>(Sb, Vg, OT, ZB);

  // 6. output assembly
  basewrite_kernel<<<2048, 256, 0, stream>>>(BASE, out);
  corr_kernel<<<dim3(B_ * NH, 4), 256, 0, stream>>>(OT, ZB, MV, Wo, TOPI, out);
}

// Round 10
// 899.034 us; speedup vs baseline: 1.0746x; 1.0746x over previous
//
#include <hip/hip_runtime.h>
#include <cfloat>
#include <cstdint>

#define B_  8
#define L_  4096
#define DM  1024
#define NH  16
#define DH  64
#define SK  45

typedef __attribute__((ext_vector_type(4))) float f32x4;
typedef _Float16 f16;
typedef __attribute__((ext_vector_type(4))) _Float16 f16x4;
typedef __attribute__((ext_vector_type(8))) _Float16 f16x8;

__device__ __forceinline__ void gload_lds16(const void* g, void* l) {
  __builtin_amdgcn_global_load_lds(
      (const __attribute__((address_space(1))) unsigned int*)g,
      (__attribute__((address_space(3))) unsigned int*)l, 16, 0, 0);
}

// XOR-swizzled f16 index into a [rows][32] f16 tile (64B rows), granule 8 f16.
__device__ __forceinline__ int swz(int row, int c) {
  return row * 32 + (c ^ (((row >> 1) & 3) << 3));
}

// ---------------- x f32 -> f16 hi ----------------
__global__ __launch_bounds__(256) void xsplit16_kernel(const float* __restrict__ x,
    f16* __restrict__ xh, int n4) {
  int i = blockIdx.x * 256 + threadIdx.x;
  int stride = gridDim.x * 256;
  for (; i < n4; i += stride) {
    f32x4 v = ((const f32x4*)x)[i];
    f16x4 h;
    #pragma unroll
    for (int j = 0; j < 4; ++j) h[j] = (f16)v[j];
    ((f16x4*)xh)[i] = h;
  }
}

// ---------------- W f32 -> f16 hi (+ scaled lo) ----------------
__global__ __launch_bounds__(256) void wsplit16_kernel(const float* __restrict__ w,
    f16* __restrict__ wh, f16* __restrict__ wl, int n4, int withlo) {
  int i = blockIdx.x * 256 + threadIdx.x;
  int stride = gridDim.x * 256;
  for (; i < n4; i += stride) {
    f32x4 v = ((const f32x4*)w)[i];
    f16x4 h, l;
    #pragma unroll
    for (int j = 0; j < 4; ++j) {
      h[j] = (f16)v[j];
      l[j] = (f16)((v[j] - (float)h[j]) * 2048.0f);
    }
    ((f16x4*)wh)[i] = h;
    if (withlo) ((f16x4*)wl)[i] = l;
  }
}

// ---------------- mean over L from XH (f16) ----------------
__global__ __launch_bounds__(256) void meansum_kernel(const f16* __restrict__ xh,
                                                      float* __restrict__ meanx) {
  int b = blockIdx.x;
  int d = blockIdx.y * 256 + threadIdx.x;
  int l0 = blockIdx.z * 256;
  const f16* p = xh + ((size_t)b * L_ + l0) * DM + d;
  float s = 0.f;
  for (int i = 0; i < 256; ++i) s += (float)p[(size_t)i * DM];
  atomicAdd(&meanx[b * DM + d], s);
}

// f32 mean fallback (small-ws diagnostic path)
__global__ __launch_bounds__(256) void meansum32_kernel(const float* __restrict__ x,
                                                        float* __restrict__ meanx) {
  int b = blockIdx.x;
  int d = blockIdx.y * 256 + threadIdx.x;
  int l0 = blockIdx.z * 256;
  const float* p = x + ((size_t)b * L_ + l0) * DM + d;
  float s = 0.f;
  for (int i = 0; i < 256; ++i) s += p[(size_t)i * DM];
  atomicAdd(&meanx[b * DM + d], s);
}

// vout(b,n) = (vin(b,:) . W[n,:]) * scale + bias[n]
__global__ __launch_bounds__(256) void proj_vec_kernel(const float* __restrict__ vin,
    const float* __restrict__ W, const float* __restrict__ bias,
    float* __restrict__ vout, float scale) {
  int g = blockIdx.x * 256 + threadIdx.x;
  int b = g >> 10, n = g & 1023;
  const float* xr = vin + b * DM;
  const float* wr = W + (size_t)n * DM;
  float a0 = 0, a1 = 0, a2 = 0, a3 = 0;
  for (int d = 0; d < DM; d += 4) {
    a0 += xr[d + 0] * wr[d + 0];
    a1 += xr[d + 1] * wr[d + 1];
    a2 += xr[d + 2] * wr[d + 2];
    a3 += xr[d + 3] * wr[d + 3];
  }
  vout[g] = ((a0 + a1) + (a2 + a3)) * scale + bias[n];
}

// ---------------- Q projection: f16-split GEMM, BK=32 (proven best) ---------------
__global__ __launch_bounds__(256, 2) void gemm_qsplit(const float* __restrict__ x,
    const f16* __restrict__ WQH, const f16* __restrict__ WQL,
    const float* __restrict__ bq, float* __restrict__ Qout) {
  __shared__ f16 xh[128 * 32];
  __shared__ f16 xl[128 * 32];
  __shared__ f16 wh[128 * 32];
  __shared__ f16 wl[128 * 32];
  const int tid = threadIdx.x;
  const int g = blockIdx.y * 8 + blockIdx.x;    // hw linear id; XCD = g & 7
  const int q = g >> 3;
  const int nt = q & 7;                         // n-tile cycles fastest
  const int mt = (g & 7) + (q >> 3) * 8;        // panel pinned to XCD g&7
  const int n0 = nt * 128;
  const int m0 = mt * 128;
  const int lane = tid & 63;
  const int wave = tid >> 6;
  const int wr = (wave >> 1) * 64;
  const int wc = (wave & 1) * 64;
  const int frow = lane & 15;
  const int fk = (lane >> 4) * 8;

  f32x4 aH[4][4], aL[4][4];
  #pragma unroll
  for (int i = 0; i < 4; ++i)
    #pragma unroll
    for (int j = 0; j < 4; ++j)
      #pragma unroll
      for (int z = 0; z < 4; ++z) { aH[i][j][z] = 0.f; aL[i][j][z] = 0.f; }

  const int ar = tid >> 1;            // 0..127
  const int ac = (tid & 1) * 16;      // 0 / 16
  const int r2 = tid >> 2;            // 0..63
  const int cb = (tid & 3) * 8;
  const int cbs = cb ^ (((r2 >> 1) & 3) << 3);   // pre-swizzled source col

  for (int kt = 0; kt < 32; ++kt) {
    const float* gx = x + (size_t)(m0 + ar) * DM + kt * 32 + ac;
    #pragma unroll
    for (int gi = 0; gi < 4; ++gi) {
      f32x4 v = ((const f32x4*)gx)[gi];
      f16x4 h, l;
      #pragma unroll
      for (int z = 0; z < 4; ++z) {
        h[z] = (f16)v[z];
        l[z] = (f16)((v[z] - (float)h[z]) * 2048.0f);
      }
      *(f16x4*)(xh + swz(ar, ac + gi * 4)) = h;
      *(f16x4*)(xl + swz(ar, ac + gi * 4)) = l;
    }
    gload_lds16(WQH + (size_t)(n0 + r2) * DM + kt * 32 + cbs,      wh + r2 * 32 + cb);
    gload_lds16(WQH + (size_t)(n0 + r2 + 64) * DM + kt * 32 + cbs, wh + (r2 + 64) * 32 + cb);
    gload_lds16(WQL + (size_t)(n0 + r2) * DM + kt * 32 + cbs,      wl + r2 * 32 + cb);
    gload_lds16(WQL + (size_t)(n0 + r2 + 64) * DM + kt * 32 + cbs, wl + (r2 + 64) * 32 + cb);
    __syncthreads();
    f16x8 ah[4], al[4], bh[4], bl[4];
    #pragma unroll
    for (int mi = 0; mi < 4; ++mi) {
      ah[mi] = *(const f16x8*)(xh + swz(wr + mi * 16 + frow, fk));
      al[mi] = *(const f16x8*)(xl + swz(wr + mi * 16 + frow, fk));
    }
    #pragma unroll
    for (int ni = 0; ni < 4; ++ni) {
      bh[ni] = *(const f16x8*)(wh + swz(wc + ni * 16 + frow, fk));
      bl[ni] = *(const f16x8*)(wl + swz(wc + ni * 16 + frow, fk));
    }
    #pragma unroll
    for (int mi = 0; mi < 4; ++mi)
      #pragma unroll
      for (int ni = 0; ni < 4; ++ni) {
        aH[mi][ni] = __builtin_amdgcn_mfma_f32_16x16x32_f16(ah[mi], bh[ni], aH[mi][ni], 0, 0, 0);
        aL[mi][ni] = __builtin_amdgcn_mfma_f32_16x16x32_f16(ah[mi], bl[ni], aL[mi][ni], 0, 0, 0);
        aL[mi][ni] = __builtin_amdgcn_mfma_f32_16x16x32_f16(al[mi], bh[ni], aL[mi][ni], 0, 0, 0);
      }
    __syncthreads();
  }

  #pragma unroll
  for (int mi = 0; mi < 4; ++mi) {
    int rowb = m0 + wr + mi * 16 + (lane >> 4) * 4;
    #pragma unroll
    for (int ni = 0; ni < 4; ++ni) {
      int col = n0 + wc + ni * 16 + (lane & 15);
      int h = col >> 6, d = col & 63;
      float bc = bq[col];
      #pragma unroll
      for (int j = 0; j < 4; ++j) {
        int rr = rowb + j;
        int b = rr >> 12;
        int l = rr & 4095;
        Qout[(((size_t)b * NH + h) * L_ + (size_t)l) * DH + d] =
            aH[mi][ni][j] + aL[mi][ni][j] * (1.0f / 2048.0f) + bc;
      }
    }
  }
}

// ---------------- k_sample rows, f32 LDS-tiled: KS[b][s][n] ----------------
__global__ __launch_bounds__(256, 4) void ksample_kernel(const float* __restrict__ x,
    const float* __restrict__ Wk, const float* __restrict__ bk,
    const int* __restrict__ sidx, float* __restrict__ KS) {
  const int b = blockIdx.x, nc = blockIdx.y, sg = blockIdx.z;
  __shared__ float xs[5][32];
  __shared__ float wk[64][33];
  __shared__ float red[4][5][64];
  __shared__ int ls[5];
  const int tid = threadIdx.x;
  const int nl = tid & 63, kq = tid >> 6;
  if (tid < 5) ls[tid] = sidx[sg * 5 + tid];
  float acc[5] = {0.f, 0.f, 0.f, 0.f, 0.f};
  const int wrow = tid >> 2, wq = tid & 3;
  for (int kt = 0; kt < 32; ++kt) {
    const int d0 = kt * 32;
    __syncthreads();
    if (tid < 40) {
      int s = tid >> 3, q = tid & 7;
      *(f32x4*)&xs[s][q * 4] = *(const f32x4*)&x[((size_t)b * L_ + ls[s]) * DM + d0 + q * 4];
    }
    {
      const float* src = &Wk[(size_t)(nc * 64 + wrow) * DM + d0 + wq * 8];
      *(f32x4*)&wk[wrow][wq * 8]     = *(const f32x4*)src;
      *(f32x4*)&wk[wrow][wq * 8 + 4] = *(const f32x4*)(src + 4);
    }
    __syncthreads();
    #pragma unroll
    for (int i = 0; i < 2; ++i) {
      f32x4 w = *(const f32x4*)&wk[nl][kq * 8 + i * 4];
      #pragma unroll
      for (int s = 0; s < 5; ++s) {
        f32x4 xv = *(const f32x4*)&xs[s][kq * 8 + i * 4];
        acc[s] += xv[0] * w[0] + xv[1] * w[1] + xv[2] * w[2] + xv[3] * w[3];
      }
    }
  }
  #pragma unroll
  for (int s = 0; s < 5; ++s) red[kq][s][nl] = acc[s];
  __syncthreads();
  for (int t = tid; t < 5 * 64; t += 256) {
    int s = t >> 6, j = t & 63;
    int nj = nc * 64 + j;
    KS[((size_t)b * SK + sg * 5 + s) * DM + nj] =
        red[0][s][j] + red[1][s][j] + red[2][s][j] + red[3][s][j] + bk[nj];
  }
}

// ---------------- m = max_s - mean_s of (q . k_sample)*scale ----------------
__global__ __launch_bounds__(256, 4) void msample_kernel(const float* __restrict__ Q,
    const float* __restrict__ KS, float* __restrict__ Mout) {
  __shared__ float ks[SK * DH];
  const int bh = blockIdx.x;
  const int b = bh >> 4, h = bh & 15;
  const int tid = threadIdx.x;
  for (int i = tid; i < SK * DH; i += 256) {
    int s = i >> 6, d = i & 63;
    ks[i] = KS[((size_t)b * SK + s) * DM + h * DH + d];
  }
  __syncthreads();
  const int l = blockIdx.y * 256 + tid;
  const float* qr = Q + ((size_t)bh * L_ + l) * DH;
  f32x4 q[16];
  #pragma unroll
  for (int i = 0; i < 16; ++i) q[i] = ((const f32x4*)qr)[i];
  float mx = -FLT_MAX, sum = 0.f;
  for (int s = 0; s < SK; ++s) {
    const f32x4* kk = (const f32x4*)(ks + s * DH);
    float d0 = 0, d1 = 0, d2 = 0, d3 = 0;
    #pragma unroll
    for (int i = 0; i < 16; ++i) {
      f32x4 kv = kk[i];
      d0 += q[i][0] * kv[0];
      d1 += q[i][1] * kv[1];
      d2 += q[i][2] * kv[2];
      d3 += q[i][3] * kv[3];
    }
    float dot = ((d0 + d1) + (d2 + d3)) * 0.125f;
    mx = fmaxf(mx, dot);
    sum += dot;
  }
  Mout[(size_t)bh * L_ + l] = mx - sum * (1.0f / SK);
}

// ---------------- top-45 per (b,h): iterative argmax ----------------
__global__ __launch_bounds__(256) void topk_kernel(const float* __restrict__ M,
                                                   int* __restrict__ topi) {
  __shared__ float vals[L_];
  __shared__ float wv[4];
  __shared__ int wi[4];
  const int bh = blockIdx.x, tid = threadIdx.x;
  for (int i = tid; i < L_; i += 256) vals[i] = M[(size_t)bh * L_ + i];
  __syncthreads();
  const int lane = tid & 63, wave = tid >> 6;
  for (int it = 0; it < SK; ++it) {
    float best = -FLT_MAX;
    int bi = 1 << 30;
    for (int i = tid; i < L_; i += 256) {
      float v = vals[i];
      if (v > best || (v == best && i < bi)) { best = v; bi = i; }
    }
    #pragma unroll
    for (int off = 32; off; off >>= 1) {
      float ov = __shfl_down(best, off);
      int oi = __shfl_down(bi, off);
      if (ov > best || (ov == best && oi < bi)) { best = ov; bi = oi; }
    }
    if (lane == 0) { wv[wave] = best; wi[wave] = bi; }
    __syncthreads();
    if (tid == 0) {
      float bb = wv[0]; int bj = wi[0];
      for (int w = 1; w < 4; ++w)
        if (wv[w] > bb || (wv[w] == bb && wi[w] < bj)) { bb = wv[w]; bj = wi[w]; }
      topi[bh * SK + it] = bj;
      vals[bj] = -FLT_MAX;
    }
    __syncthreads();
  }
}

// ---------------- gather top-45 q rows per (b,h) into f16 QT[bh][48][64] ----------
__global__ __launch_bounds__(256) void gatherq_kernel(const float* __restrict__ Q,
    const int* __restrict__ topi, f16* __restrict__ QT) {
  const int bh = blockIdx.x, tid = threadIdx.x;
  for (int i = tid; i < 48 * 64; i += 256) {
    int u = i >> 6, d = i & 63;
    float v = 0.f;
    if (u < SK) {
      int l = topi[bh * SK + u];
      v = Q[((size_t)bh * L_ + l) * DH + d];
    }
    QT[bh * 3072 + i] = (f16)v;
  }
}

// ---------------- fused K+V GEMM + raw scores: S f16, V f16 (d-major) to d_out ----
__global__ __launch_bounds__(256, 2) void kscore_kernel(const f16* __restrict__ XH,
    const f16* __restrict__ WKH, const f16* __restrict__ WVH,
    const float* __restrict__ bk, const float* __restrict__ bvec,
    const f16* __restrict__ QT, f16* __restrict__ S, f16* __restrict__ Vg) {
  __shared__ __align__(16) char smem[68352];
  f16* qs = (f16*)smem;
  f16* xh = (f16*)(smem + 6912);
  f16* wh = (f16*)(smem + 23296);
  f16* Kt = (f16*)(smem + 31488);
  f16* Vt = Kt;
  const int g = blockIdx.y * 128 + blockIdx.x;  // XCD = g & 7
  const int b = g & 7;
  const int p = g >> 3;
  const int jc = p >> 4;
  const int h = p & 15;
  const int bh = b * 16 + h;
  const int tid = threadIdx.x;
  const int lane = tid & 63, wave = tid >> 6;
  const int frow = lane & 15;
  const int fk = (lane >> 4) * 8;

  for (int i = tid; i < 48 * 64; i += 256)
    qs[(i >> 6) * 72 + (i & 63)] = QT[bh * 3072 + i];

  f32x4 accK[4][4], accV[4][4];
  #pragma unroll
  for (int i = 0; i < 4; ++i)
    #pragma unroll
    for (int j = 0; j < 4; ++j)
      #pragma unroll
      for (int z = 0; z < 4; ++z) { accK[i][j][z] = 0.f; accV[i][j][z] = 0.f; }

  const int r2 = tid >> 2, cb = (tid & 3) * 8;
  const int cbs = cb ^ (((r2 >> 1) & 3) << 3);
  for (int kt = 0; kt < 32; ++kt) {
    #pragma unroll
    for (int i = 0; i < 4; ++i)
      gload_lds16(XH + (size_t)(b * L_ + jc * 256 + i * 64 + r2) * DM + kt * 32 + cbs,
                  xh + (i * 64 + r2) * 32 + cb);
    gload_lds16(WKH + (size_t)(h * 64 + r2) * DM + kt * 32 + cbs, wh + r2 * 32 + cb);
    gload_lds16(WVH + (size_t)(h * 64 + r2) * DM + kt * 32 + cbs, wh + (r2 + 64) * 32 + cb);
    __syncthreads();
    f16x8 am[4], bnK[4], bnV[4];
    #pragma unroll
    for (int mi = 0; mi < 4; ++mi)
      am[mi] = *(const f16x8*)(xh + swz(wave * 64 + mi * 16 + frow, fk));
    #pragma unroll
    for (int ni = 0; ni < 4; ++ni) {
      bnK[ni] = *(const f16x8*)(wh + swz(ni * 16 + frow, fk));
      bnV[ni] = *(const f16x8*)(wh + swz(64 + ni * 16 + frow, fk));
    }
    #pragma unroll
    for (int mi = 0; mi < 4; ++mi)
      #pragma unroll
      for (int ni = 0; ni < 4; ++ni) {
        accK[mi][ni] = __builtin_amdgcn_mfma_f32_16x16x32_f16(am[mi], bnK[ni], accK[mi][ni], 0, 0, 0);
        accV[mi][ni] = __builtin_amdgcn_mfma_f32_16x16x32_f16(am[mi], bnV[ni], accV[mi][ni], 0, 0, 0);
      }
    __syncthreads();
  }

  #pragma unroll
  for (int mi = 0; mi < 4; ++mi) {
    int jl = wave * 64 + mi * 16 + (lane >> 4) * 4;
    #pragma unroll
    for (int ni = 0; ni < 4; ++ni) {
      int d = ni * 16 + (lane & 15);
      float bc = bk[h * 64 + d];
      #pragma unroll
      for (int z = 0; z < 4; ++z)
        Kt[(jl + z) * 72 + d] = (f16)(accK[mi][ni][z] + bc);
    }
  }
  __syncthreads();

  f32x4 accS[3][4];
  #pragma unroll
  for (int i = 0; i < 3; ++i)
    #pragma unroll
    for (int j = 0; j < 4; ++j)
      #pragma unroll
      for (int z = 0; z < 4; ++z) accS[i][j][z] = 0.f;
  #pragma unroll
  for (int ks = 0; ks < 2; ++ks) {
    f16x8 aq[3], bv[4];
    #pragma unroll
    for (int mu = 0; mu < 3; ++mu)
      aq[mu] = *(const f16x8*)(qs + (mu * 16 + frow) * 72 + ks * 32 + fk);
    #pragma unroll
    for (int nj = 0; nj < 4; ++nj)
      bv[nj] = *(const f16x8*)(Kt + (wave * 64 + nj * 16 + frow) * 72 + ks * 32 + fk);
    #pragma unroll
    for (int mu = 0; mu < 3; ++mu)
      #pragma unroll
      for (int nj = 0; nj < 4; ++nj)
        accS[mu][nj] = __builtin_amdgcn_mfma_f32_16x16x32_f16(aq[mu], bv[nj], accS[mu][nj], 0, 0, 0);
  }
  __syncthreads();   // all Kt/qs reads done before Vt (aliased) is written

  #pragma unroll
  for (int mi = 0; mi < 4; ++mi) {
    int jl = wave * 64 + mi * 16 + (lane >> 4) * 4;
    #pragma unroll
    for (int ni = 0; ni < 4; ++ni) {
      int d = ni * 16 + (lane & 15);
      float bc = bvec[h * 64 + d];
      #pragma unroll
      for (int z = 0; z < 4; ++z)
        Vt[d * 264 + jl + z] = (f16)(accV[mi][ni][z] + bc);
    }
  }
  __syncthreads();

  for (int t = tid; t < 64 * 32; t += 256) {
    int d = t >> 5, j8 = t & 31;
    f16x8 v = *(const f16x8*)(Vt + d * 264 + j8 * 8);
    *(f16x8*)(Vg + ((size_t)bh * 64 + d) * L_ + jc * 256 + j8 * 8) = v;
  }

  #pragma unroll
  for (int mu = 0; mu < 3; ++mu) {
    #pragma unroll
    for (int nj = 0; nj < 4; ++nj) {
      int j = jc * 256 + wave * 64 + nj * 16 + (lane & 15);
      #pragma unroll
      for (int z = 0; z < 4; ++z) {
        int u = mu * 16 + (lane >> 4) * 4 + z;
        if (u < SK)
          S[((size_t)bh * SK + u) * L_ + j] = (f16)(accS[mu][nj][z] * 0.125f);
      }
    }
  }
}

// ---------------- PV: unnormalized exp, Z via atomics, V from global --------------
__global__ __launch_bounds__(256, 2) void pv_kernel(const f16* __restrict__ S,
    const f16* __restrict__ Vg, float* __restrict__ OT, float* __restrict__ Zb) {
  __shared__ float red[4 * 48 * 64];
  const int g = blockIdx.y * 128 + blockIdx.x;
  const int b = g & 7;
  const int p = g >> 3;
  const int jc = p >> 4;
  const int h = p & 15;
  const int bh = b * 16 + h;
  const int tid = threadIdx.x;
  const int lane = tid & 63, wave = tid >> 6;
  const int frow = lane & 15;
  const int fk = (lane >> 4) * 8;

  f32x4 accO[3][4];
  float zacc[3] = {0.f, 0.f, 0.f};
  #pragma unroll
  for (int i = 0; i < 3; ++i)
    #pragma unroll
    for (int j = 0; j < 4; ++j)
      #pragma unroll
      for (int z = 0; z < 4; ++z) accO[i][j][z] = 0.f;

  #pragma unroll
  for (int ks = 0; ks < 2; ++ks) {
    f16x8 ap[3], bv[4];
    #pragma unroll
    for (int mu = 0; mu < 3; ++mu) {
      int urow = mu * 16 + frow;
      int ur = (urow < SK) ? urow : 0;
      const f16* aptr = S + ((size_t)bh * SK + ur) * L_ + jc * 256 + wave * 64 + ks * 32 + fk;
      f16x8 raw = *(const f16x8*)aptr;
      f16x8 pp;
      float zs = 0.f;
      #pragma unroll
      for (int j = 0; j < 8; ++j) {
        f16 e = (f16)__expf((float)raw[j]);
        pp[j] = e;
        zs += (float)e;
      }
      zacc[mu] += zs;
      ap[mu] = pp;
    }
    #pragma unroll
    for (int nd = 0; nd < 4; ++nd)
      bv[nd] = *(const f16x8*)(Vg + ((size_t)bh * 64 + nd * 16 + frow) * L_ +
                               jc * 256 + wave * 64 + ks * 32 + fk);
    #pragma unroll
    for (int mu = 0; mu < 3; ++mu)
      #pragma unroll
      for (int nd = 0; nd < 4; ++nd)
        accO[mu][nd] = __builtin_amdgcn_mfma_f32_16x16x32_f16(ap[mu], bv[nd], accO[mu][nd], 0, 0, 0);
  }

  // Z partials: reduce the 4 lane-groups sharing a row, one atomic per row
  #pragma unroll
  for (int mu = 0; mu < 3; ++mu) {
    float z = zacc[mu];
    z += __shfl_xor(z, 16);
    z += __shfl_xor(z, 32);
    int u = mu * 16 + frow;
    if ((lane >> 4) == 0 && u < SK) atomicAdd(&Zb[bh * 48 + u], z);
  }

  #pragma unroll
  for (int mu = 0; mu < 3; ++mu) {
    #pragma unroll
    for (int nd = 0; nd < 4; ++nd) {
      int d = nd * 16 + (lane & 15);
      #pragma unroll
      for (int z = 0; z < 4; ++z) {
        int u = mu * 16 + (lane >> 4) * 4 + z;
        red[wave * 3072 + u * 64 + d] = accO[mu][nd][z];
      }
    }
  }
  __syncthreads();
  for (int i = tid; i < 3072; i += 256) {
    int u = i >> 6;
    if (u < SK)
      atomicAdd(&OT[((size_t)bh * SK + u) * DH + (i & 63)],
                red[i] + red[3072 + i] + red[6144 + i] + red[9216 + i]);
  }
}

// ---------------- out = broadcast(base) ----------------
__global__ __launch_bounds__(256) void basewrite_kernel(const float* __restrict__ base,
                                                        float* __restrict__ out) {
  size_t i = (size_t)blockIdx.x * 256 + threadIdx.x;
  const size_t stride = (size_t)gridDim.x * 256;
  const size_t total = (size_t)B_ * L_ * (DM / 4);
  for (; i < total; i += stride) {
    size_t b = i >> 20;
    size_t c = i & 255;
    ((f32x4*)out)[i] = ((const f32x4*)base)[b * 256 + c];
  }
}

// ---------------- corrections: out[b, top_u, n] += (OT/Z - MV) . Wo[n, h*64:] -----
__global__ __launch_bounds__(256, 2) void corr_kernel(const float* __restrict__ OT,
    const float* __restrict__ Zb, const float* __restrict__ MV,
    const float* __restrict__ Wo, const int* __restrict__ topi,
    float* __restrict__ out) {
  __shared__ float dv[SK][64];
  __shared__ float wo[64][65];
  __shared__ float invz[SK];
  __shared__ int lidx[SK];
  const int bh = blockIdx.x, q = blockIdx.y, tid = threadIdx.x;
  const int b = bh >> 4, h = bh & 15;
  if (tid < SK) {
    invz[tid] = 1.0f / Zb[bh * 48 + tid];
    lidx[tid] = topi[bh * SK + tid];
  }
  __syncthreads();
  for (int i = tid; i < SK * 64; i += 256) {
    int u = i >> 6, d = i & 63;
    dv[u][d] = OT[((size_t)bh * SK + u) * DH + d] * invz[u] - MV[b * DM + h * DH + d];
  }
  const int nn = tid & 63, ug = tid >> 6;
  for (int c = 0; c < 4; ++c) {
    const int n0 = q * 256 + c * 64;
    __syncthreads();
    for (int t = tid; t < 1024; t += 256) {
      int row = t >> 4, vc = t & 15;
      f32x4 v = *(const f32x4*)&Wo[(size_t)(n0 + row) * DM + h * DH + vc * 4];
      *(f32x4*)&wo[row][vc * 4] = v;
    }
    __syncthreads();
    #pragma unroll
    for (int i = 0; i < 12; ++i) {
      int u = ug + i * 4;
      if (u >= SK) break;
      float a0 = 0, a1 = 0, a2 = 0, a3 = 0;
      #pragma unroll
      for (int d4 = 0; d4 < 16; ++d4) {
        f32x4 w = *(const f32x4*)&wo[nn][d4 * 4];
        f32x4 dd = *(const f32x4*)&dv[u][d4 * 4];
        a0 += dd[0] * w[0]; a1 += dd[1] * w[1];
        a2 += dd[2] * w[2]; a3 += dd[3] * w[3];
      }
      atomicAdd(&out[((size_t)b * L_ + lidx[u]) * DM + n0 + nn], (a0 + a1) + (a2 + a3));
    }
  }
}

// ---------------- workspace layout ----------------
static const size_t OFF_XH   = 0;                        // 67108864
static const size_t OFF_WQH  = OFF_XH + 67108864;        // 2097152
static const size_t OFF_WQL  = OFF_WQH + 2097152;
static const size_t OFF_WKH  = OFF_WQL + 2097152;
static const size_t OFF_WVH  = OFF_WKH + 2097152;
static const size_t OFF_KS   = OFF_WVH + 2097152;        // 1474560
static const size_t OFF_M    = OFF_KS + 1474560;         // 2097152
static const size_t OFF_TOPI = OFF_M + 2097152;          // 23040
static const size_t OFF_MEANX= OFF_TOPI + 23040;         // 32768
static const size_t OFF_MV   = OFF_MEANX + 32768;
static const size_t OFF_BASE = OFF_MV + 32768;
static const size_t OFF_ZB   = OFF_BASE + 32768;         // 128*48*4 = 24576
static const size_t OFF_QT   = OFF_ZB + 24576;           // 786432
static const size_t OFF_S    = OFF_QT + 786432;          // 47185920
static const size_t OFF_OT   = OFF_S + 47185920;         // 1474560
static const size_t WS_NEED  = OFF_OT + 1474560;

extern "C" void kernel_launch(void* const* d_in, const int* in_sizes, int n_in,
                              void* d_out, int out_size, void* d_ws, size_t ws_size,
                              hipStream_t stream) {
  const float* x  = (const float*)d_in[0];
  const float* Wq = (const float*)d_in[1];
  const float* bq = (const float*)d_in[2];
  const float* Wk = (const float*)d_in[3];
  const float* bk = (const float*)d_in[4];
  const float* Wv = (const float*)d_in[5];
  const float* bv = (const float*)d_in[6];
  const float* Wo = (const float*)d_in[7];
  const float* bo = (const float*)d_in[8];
  const int* sidx = (const int*)d_in[9];
  float* out = (float*)d_out;
  char* ws = (char*)d_ws;

  if (ws_size < WS_NEED) {
    if (ws_size < 131072) return;
    float* MEANX = (float*)(ws + 0);
    float* MV    = (float*)(ws + 32768);
    float* BASE  = (float*)(ws + 65536);
    hipMemsetAsync(MEANX, 0, 32768, stream);
    meansum32_kernel<<<dim3(B_, 4, 16), 256, 0, stream>>>(x, MEANX);
    proj_vec_kernel<<<32, 256, 0, stream>>>(MEANX, Wv, bv, MV, 1.0f / L_);
    proj_vec_kernel<<<32, 256, 0, stream>>>(MV, Wo, bo, BASE, 1.0f);
    basewrite_kernel<<<2048, 256, 0, stream>>>(BASE, out);
    return;
  }

  f16*   XH   = (f16*)(ws + OFF_XH);
  f16*   WQH  = (f16*)(ws + OFF_WQH);
  f16*   WQL  = (f16*)(ws + OFF_WQL);
  f16*   WKH  = (f16*)(ws + OFF_WKH);
  f16*   WVH  = (f16*)(ws + OFF_WVH);
  float* KS   = (float*)(ws + OFF_KS);
  float* Mb   = (float*)(ws + OFF_M);
  int*   TOPI = (int*)(ws + OFF_TOPI);
  float* MEANX= (float*)(ws + OFF_MEANX);
  float* MV   = (float*)(ws + OFF_MV);
  float* BASE = (float*)(ws + OFF_BASE);
  float* ZB   = (float*)(ws + OFF_ZB);
  f16*   QT   = (f16*)(ws + OFF_QT);
  f16*   Sb   = (f16*)(ws + OFF_S);
  float* OT   = (float*)(ws + OFF_OT);
  float* Qout = out;         // Q lives in d_out until gatherq
  f16*   Vg   = (f16*)out;   // V (67 MB) reuses d_out after Q is dead

  // 1. conversions / splits / zeroing
  xsplit16_kernel<<<2048, 256, 0, stream>>>(x, XH, (int)((size_t)B_ * L_ * DM / 4));
  wsplit16_kernel<<<256, 256, 0, stream>>>(Wq, WQH, WQL, DM * DM / 4, 1);
  wsplit16_kernel<<<256, 256, 0, stream>>>(Wk, WKH, WKH, DM * DM / 4, 0);
  wsplit16_kernel<<<256, 256, 0, stream>>>(Wv, WVH, WVH, DM * DM / 4, 0);
  hipMemsetAsync(MEANX, 0, 32768, stream);
  hipMemsetAsync(OT, 0, 1474560, stream);
  hipMemsetAsync(ZB, 0, 24576, stream);

  // 2. mean path (reads XH f16)
  meansum_kernel<<<dim3(B_, 4, 16), 256, 0, stream>>>(XH, MEANX);
  proj_vec_kernel<<<32, 256, 0, stream>>>(MEANX, Wv, bv, MV, 1.0f / L_);
  proj_vec_kernel<<<32, 256, 0, stream>>>(MV, Wo, bo, BASE, 1.0f);

  // 3. Q projection (f16-split) -> d_out
  gemm_qsplit<<<dim3(8, 256), 256, 0, stream>>>(x, WQH, WQL, bq, Qout);

  // 4. sampled K rows + m + top-k + q_top gather (Q dead after this)
  ksample_kernel<<<dim3(B_, 16, 9), 256, 0, stream>>>(x, Wk, bk, sidx, KS);
  msample_kernel<<<dim3(B_ * NH, L_ / 256), 256, 0, stream>>>(Qout, KS, Mb);
  topk_kernel<<<B_ * NH, 256, 0, stream>>>(Mb, TOPI);
  gatherq_kernel<<<B_ * NH, 256, 0, stream>>>(Qout, TOPI, QT);

  // 5. fused K+V GEMM + raw scores (V -> d_out), PV with inline exp + Z
  kscore_kernel<<<dim3(128, 16), 256, 0, stream>>>(XH, WKH, WVH, bk, bv, QT, Sb, Vg);
  pv_kernel<<<dim3(128, 16), 256, 0, stream>>>(Sb, Vg, OT, ZB);

  // 6. output assembly
  basewrite_kernel<<<2048, 256, 0, stream>>>(BASE, out);
  corr_kernel<<<dim3(B_ * NH, 4), 256, 0, stream>>>(OT, ZB, MV, Wo, TOPI, out);
}